// Round 4
// baseline (1812.570 us; speedup 1.0000x reference)
//
#include <hip/hip_runtime.h>
#include <hip/hip_bf16.h>

typedef unsigned short u16;
typedef __attribute__((ext_vector_type(8))) __bf16 bf16x8;
typedef __attribute__((ext_vector_type(4))) float f32x4;

#define TOK 16384
#define DM  1024
#define HD  4096
#define NE  8
#define NG  128
#define GSZ 128
#define CAPM 31              // CAP-1 usable slots per (group, expert)
#define ME  (NG*CAPM)        // 3968 rows per expert

static __device__ __forceinline__ u16 f2b(float f) {
  union { float f; unsigned u; } v; v.f = f;
  unsigned r = v.u + 0x7fffu + ((v.u >> 16) & 1u);
  return (u16)(r >> 16);
}

// jax.nn.gelu default = tanh approximation
static __device__ __forceinline__ float gelu_f(float x) {
  float y = 0.7978845608028654f * (x + 0.044715f * x * x * x);
  float t = __expf(-2.0f * fabsf(y));          // e^{-2|y|}, no overflow
  float th = (1.0f - t) / (1.0f + t);
  th = (y < 0.0f) ? -th : th;
  return 0.5f * x * (1.0f + th);
}

static __device__ __forceinline__ void gl2lds16(const void* g, void* l) {
  __builtin_amdgcn_global_load_lds(
      (const __attribute__((address_space(1))) void*)g,
      (__attribute__((address_space(3))) void*)l, 16, 0, 0);
}

// ---------------- router: logits (fp64 accum), softmax, top-2 ----------------
__global__ __launch_bounds__(256) void k_router(
    const float* __restrict__ x, const float* __restrict__ gw,
    const float* __restrict__ gb, int* __restrict__ e_sel,
    float* __restrict__ gsel) {
  int wave = threadIdx.x >> 6, lane = threadIdx.x & 63;
  int t = blockIdx.x * 4 + wave;
  const float* xr = x + (size_t)t * DM;
  double acc[8] = {0,0,0,0,0,0,0,0};
  for (int d0 = lane * 4; d0 < DM; d0 += 256) {
    float4 xv = *(const float4*)(xr + d0);
    float xa[4] = {xv.x, xv.y, xv.z, xv.w};
    const float* g0 = gw + (size_t)d0 * NE;
#pragma unroll
    for (int dd = 0; dd < 4; ++dd)
#pragma unroll
      for (int e = 0; e < 8; ++e)
        acc[e] += (double)xa[dd] * (double)g0[dd * 8 + e];
  }
#pragma unroll
  for (int off = 32; off > 0; off >>= 1)
#pragma unroll
    for (int e = 0; e < 8; ++e)
      acc[e] += __shfl_down(acc[e], off, 64);
  if (lane == 0) {
    float l[8];
#pragma unroll
    for (int e = 0; e < 8; ++e) l[e] = (float)acc[e] + gb[e];
    int e0 = 0;
    for (int e = 1; e < 8; ++e) if (l[e] > l[e0]) e0 = e;
    int e1 = (e0 == 0) ? 1 : 0;
    for (int e = 0; e < 8; ++e) if (e != e0 && l[e] > l[e1]) e1 = e;
    float m = l[e0], s = 0.f, p[8];
    for (int e = 0; e < 8; ++e) { p[e] = expf(l[e] - m); s += p[e]; }
    e_sel[t] = e0; e_sel[TOK + t] = e1;
    gsel[t] = p[e0] / s; gsel[TOK + t] = p[e1] / s;
  }
}

// ------------- capacity assignment: serial cumsum per group, per-k ----------
__global__ void k_assign(const int* __restrict__ e_sel,
                         int* __restrict__ tok_slot, int* __restrict__ slot_tok) {
  int g = blockIdx.x;
  for (int i = threadIdx.x; i < NE * CAPM * 2; i += 64) {
    int e = i / (CAPM * 2), rem = i % (CAPM * 2), c = rem >> 1, k = rem & 1;
    slot_tok[((size_t)(e * ME + g * CAPM + c)) * 2 + k] = -1;
  }
  __syncthreads();
  if (threadIdx.x == 0) {
    int cnt[2][NE];
    for (int k = 0; k < 2; ++k) for (int e = 0; e < NE; ++e) cnt[k][e] = 0;
    for (int s = 0; s < GSZ; ++s) {
      int t = g * GSZ + s;
      for (int k = 0; k < 2; ++k) {
        int e = e_sel[k * TOK + t];
        int r = ++cnt[k][e];
        if (r <= CAPM) {
          int m = e * ME + g * CAPM + (r - 1);
          tok_slot[k * TOK + t] = m;
          slot_tok[(size_t)m * 2 + k] = t;
        } else tok_slot[k * TOK + t] = -1;
      }
    }
  }
}

// ------- exp_in[m,:] = bf16( x[t0] + x[t1] ) (slot may hold 2 tokens) -------
__global__ __launch_bounds__(128) void k_build_expin(
    const float* __restrict__ x, const int* __restrict__ slot_tok,
    u16* __restrict__ exp_in) {
  int m = blockIdx.x;
  int t0 = slot_tok[(size_t)m * 2], t1 = slot_tok[(size_t)m * 2 + 1];
  int d = threadIdx.x * 8;
  float v[8] = {0,0,0,0,0,0,0,0};
  if (t0 >= 0) {
    const float4* p = (const float4*)(x + (size_t)t0 * DM + d);
    float4 a = p[0], b = p[1];
    v[0]+=a.x; v[1]+=a.y; v[2]+=a.z; v[3]+=a.w;
    v[4]+=b.x; v[5]+=b.y; v[6]+=b.z; v[7]+=b.w;
  }
  if (t1 >= 0) {
    const float4* p = (const float4*)(x + (size_t)t1 * DM + d);
    float4 a = p[0], b = p[1];
    v[0]+=a.x; v[1]+=a.y; v[2]+=a.z; v[3]+=a.w;
    v[4]+=b.x; v[5]+=b.y; v[6]+=b.z; v[7]+=b.w;
  }
  ushort4 o0, o1;
  o0.x=f2b(v[0]); o0.y=f2b(v[1]); o0.z=f2b(v[2]); o0.w=f2b(v[3]);
  o1.x=f2b(v[4]); o1.y=f2b(v[5]); o1.z=f2b(v[6]); o1.w=f2b(v[7]);
  *(ushort4*)(exp_in + (size_t)m * DM + d) = o0;
  *(ushort4*)(exp_in + (size_t)m * DM + d + 4) = o1;
}

// ------------------------------ fp32 -> bf16 --------------------------------
__global__ __launch_bounds__(256) void k_cast_bf16(
    const float* __restrict__ in, u16* __restrict__ out, size_t n) {
  size_t i = ((size_t)blockIdx.x * 256 + threadIdx.x) * 4;
  if (i >= n) return;
  float4 v = *(const float4*)(in + i);
  ushort4 o; o.x=f2b(v.x); o.y=f2b(v.y); o.z=f2b(v.z); o.w=f2b(v.w);
  *(ushort4*)(out + i) = o;
}

// --------- transpose+cast: in(k,n) at in[k*rs+n] fp32 -> out[n*K+k] bf16 ----
__global__ __launch_bounds__(256) void k_transpose(
    const float* __restrict__ in, u16* __restrict__ out,
    int K, int N, int rs) {
  __shared__ float tile[32][33];
  int k0 = blockIdx.x * 32, n0 = blockIdx.y * 32;
  int tx = threadIdx.x & 31, ty = threadIdx.x >> 5;
#pragma unroll
  for (int i = 0; i < 4; ++i)
    tile[ty + i * 8][tx] = in[(size_t)(k0 + ty + i * 8) * rs + n0 + tx];
  __syncthreads();
#pragma unroll
  for (int i = 0; i < 4; ++i) {
    int n = ty + i * 8;
    out[(size_t)(n0 + n) * K + k0 + tx] = f2b(tile[tx][n]);
  }
}

// -------------------- bf16 MFMA GEMM, C = A(MxK) * B^T(NxK) ------------------
// 128x128 tile, BK=64, 4 waves (2x2), 16x16x32 MFMA, global_load_lds staging.
// EPI 0: bf16 out = gelu(acc + bias[col]); EPI 1: f32 out = acc + bias[col].
template <int EPI>
__global__ __launch_bounds__(256) void k_gemm(
    const u16* __restrict__ A, size_t sAe, int lda,
    const u16* __restrict__ B, size_t sBe, int ldb,
    void* __restrict__ Cv, size_t sCe, int ldc,
    const float* __restrict__ bias, int sBiasE, int K) {
  __shared__ __align__(16) u16 As[128 * 64];
  __shared__ __align__(16) u16 Bs[128 * 64];
  const int tid = threadIdx.x;
  const int lane = tid & 63, wave = tid >> 6;
  const int wr = wave >> 1, wc = wave & 1;
  const int z = blockIdx.z;
  const u16* Ab = A + (size_t)z * sAe + (size_t)(blockIdx.x * 128) * lda;
  const u16* Bb = B + (size_t)z * sBe + (size_t)(blockIdx.y * 128) * ldb;

  f32x4 acc[4][4] = {};

  for (int k0 = 0; k0 < K; k0 += 64) {
    __syncthreads();
#pragma unroll
    for (int i = 0; i < 4; ++i) {
      int cb = wave * 256 + i * 64;          // wave-uniform chunk base
      int c = cb + lane;
      int row = c >> 3, kc = (c & 7) * 8;
      gl2lds16(Ab + (size_t)row * lda + (k0 + kc), As + (size_t)cb * 8);
      gl2lds16(Bb + (size_t)row * ldb + (k0 + kc), Bs + (size_t)cb * 8);
    }
    __syncthreads();
#pragma unroll
    for (int kk = 0; kk < 64; kk += 32) {
      bf16x8 af[4], bfv[4];
#pragma unroll
      for (int mi = 0; mi < 4; ++mi)
        af[mi] = *(const bf16x8*)(As + (wr * 64 + mi * 16 + (lane & 15)) * 64 + kk + ((lane >> 4) * 8));
#pragma unroll
      for (int ni = 0; ni < 4; ++ni)
        bfv[ni] = *(const bf16x8*)(Bs + (wc * 64 + ni * 16 + (lane & 15)) * 64 + kk + ((lane >> 4) * 8));
#pragma unroll
      for (int mi = 0; mi < 4; ++mi)
#pragma unroll
        for (int ni = 0; ni < 4; ++ni)
          acc[mi][ni] = __builtin_amdgcn_mfma_f32_16x16x32_bf16(af[mi], bfv[ni], acc[mi][ni], 0, 0, 0);
    }
  }

  const int r0 = blockIdx.x * 128 + wr * 64 + ((lane >> 4) << 2);
  const int c0 = blockIdx.y * 128 + wc * 64 + (lane & 15);
#pragma unroll
  for (int ni = 0; ni < 4; ++ni) {
    int col = c0 + ni * 16;
    float bv = bias[(size_t)z * sBiasE + col];
#pragma unroll
    for (int mi = 0; mi < 4; ++mi) {
      f32x4 v = acc[mi][ni];
#pragma unroll
      for (int j = 0; j < 4; ++j) {
        int row = r0 + mi * 16 + j;
        float val = v[j] + bv;
        if (EPI == 0)
          ((u16*)Cv)[(size_t)z * sCe + (size_t)row * ldc + col] = f2b(gelu_f(val));
        else
          ((float*)Cv)[(size_t)z * sCe + (size_t)row * ldc + col] = val;
      }
    }
  }
}

// ------------------ out[t] += sum_k gate_k * eo[slot_k] ---------------------
__global__ __launch_bounds__(256) void k_combine(
    const int* __restrict__ tok_slot, const float* __restrict__ gsel,
    const float* __restrict__ eo, float* __restrict__ out) {
  int t = blockIdx.x;
  int d = threadIdx.x * 4;
  float4 v = *(float4*)(out + (size_t)t * DM + d);
#pragma unroll
  for (int k = 0; k < 2; ++k) {
    int m = tok_slot[k * TOK + t];
    if (m >= 0) {
      float g = gsel[k * TOK + t];
      float4 e = *(const float4*)(eo + (size_t)m * DM + d);
      v.x += g * e.x; v.y += g * e.y; v.z += g * e.z; v.w += g * e.w;
    }
  }
  *(float4*)(out + (size_t)t * DM + d) = v;
}

__global__ void k_report(float* out, float code) { out[0] = code; }

extern "C" void kernel_launch(void* const* d_in, const int* in_sizes, int n_in,
                              void* d_out, int out_size, void* d_ws, size_t ws_size,
                              hipStream_t stream) {
  (void)in_sizes; (void)n_in;
  const float* x     = (const float*)d_in[0];
  const float* gw    = (const float*)d_in[1];
  const float* gb    = (const float*)d_in[2];
  const float* keys  = (const float*)d_in[3];
  const float* keyb  = (const float*)d_in[4];
  const float* vals  = (const float*)d_in[5];
  const float* valb  = (const float*)d_in[6];
  const float* skey  = (const float*)d_in[7];
  const float* skeyb = (const float*)d_in[8];
  const float* sval  = (const float*)d_in[9];
  const float* svalb = (const float*)d_in[10];
  float* out = (float*)d_out;

  char* ws = (char*)d_ws;
  size_t off = 0;
  auto alloc = [&](size_t bytes) -> char* {
    char* p = ws + off; off += (bytes + 255) & ~(size_t)255; return p;
  };
  int*   e_sel    = (int*)  alloc(2 * TOK * 4);
  float* gsel     = (float*)alloc(2 * TOK * 4);
  int*   tok_slot = (int*)  alloc(2 * TOK * 4);
  int*   slot_tok = (int*)  alloc((size_t)NE * ME * 2 * 4);

  size_t off_r1 = off;                         // union region: {xb,skT,svT,exp_in} then eo
  u16* xb     = (u16*)alloc((size_t)TOK * DM * 2);
  u16* skT    = (u16*)alloc((size_t)HD * DM * 2);
  u16* svT    = (u16*)alloc((size_t)DM * HD * 2);
  u16* exp_in = (u16*)alloc((size_t)NE * ME * DM * 2);
  float* eo = (float*)(ws + off_r1);
  size_t eo_end = off_r1 + (size_t)NE * ME * DM * 4;
  if (eo_end > off) off = eo_end;

  u16* keysT = (u16*)alloc((size_t)NE * HD * DM * 2);
  u16* valsT = (u16*)alloc((size_t)NE * DM * HD * 2);

  size_t sh_b = (size_t)TOK * HD * 2;          // union region: sh then h
  size_t h_b  = (size_t)NE * ME * HD * 2;
  u16* sh = (u16*)(ws + off);
  u16* h  = (u16*)(ws + off);
  size_t need = off + (sh_b > h_b ? sh_b : h_b);

  if (need > ws_size) {                        // sentinel: out[0] = -available MB
    hipMemsetAsync(d_out, 0, (size_t)out_size * 4, stream);
    k_report<<<1, 1, 0, stream>>>(out, -(float)(ws_size >> 20));
    return;
  }

  // routing + assignment + dispatch gather
  k_router<<<TOK / 4, 256, 0, stream>>>(x, gw, gb, e_sel, gsel);
  k_assign<<<NG, 64, 0, stream>>>(e_sel, tok_slot, slot_tok);
  k_build_expin<<<NE * ME, 128, 0, stream>>>(x, slot_tok, exp_in);

  // bf16 casts / weight transposes
  k_cast_bf16<<<(TOK * DM / 4) / 256, 256, 0, stream>>>(x, xb, (size_t)TOK * DM);
  k_transpose<<<dim3(DM / 32, HD / 32), 256, 0, stream>>>(skey, skT, DM, HD, HD);
  k_transpose<<<dim3(HD / 32, DM / 32), 256, 0, stream>>>(sval, svT, HD, DM, DM);
  for (int e = 0; e < NE; ++e) {
    k_transpose<<<dim3(DM / 32, HD / 32), 256, 0, stream>>>(
        keys + (size_t)e * HD, keysT + (size_t)e * HD * DM, DM, HD, NE * HD);
    k_transpose<<<dim3(HD / 32, DM / 32), 256, 0, stream>>>(
        vals + (size_t)e * DM, valsT + (size_t)e * DM * HD, HD, DM, NE * DM);
  }

  // shared expert: out = svT( gelu(xb @ skT + skeyb) ) + svalb
  k_gemm<0><<<dim3(TOK / 128, HD / 128, 1), 256, 0, stream>>>(
      xb, 0, DM, skT, 0, DM, sh, 0, HD, skeyb, 0, DM);
  k_gemm<1><<<dim3(TOK / 128, DM / 128, 1), 256, 0, stream>>>(
      sh, 0, HD, svT, 0, HD, out, 0, DM, svalb, 0, HD);

  // MoE experts (h overwrites sh region; eo overwrites xb/skT/svT/exp_in region)
  k_gemm<0><<<dim3(ME / 128, HD / 128, NE), 256, 0, stream>>>(
      exp_in, (size_t)ME * DM, DM, keysT, (size_t)HD * DM, DM,
      h, (size_t)ME * HD, HD, keyb, HD, DM);
  k_gemm<1><<<dim3(ME / 128, DM / 128, NE), 256, 0, stream>>>(
      h, (size_t)ME * HD, HD, valsT, (size_t)DM * HD, HD,
      eo, (size_t)ME * DM, DM, valb, DM, HD);

  // combine: out += gate * eo[slot]
  k_combine<<<TOK, 256, 0, stream>>>(tok_slot, gsel, eo, out);
}

// Round 7
// 1542.409 us; speedup vs baseline: 1.1752x; 1.1752x over previous
//
#include <hip/hip_runtime.h>
#include <hip/hip_bf16.h>

typedef unsigned short u16;
typedef __attribute__((ext_vector_type(8))) __bf16 bf16x8;
typedef __attribute__((ext_vector_type(4))) float f32x4;

#define TOK 16384
#define DM  1024
#define HD  4096
#define NE  8
#define NG  128
#define GSZ 128
#define CAPM 31               // usable slots per (group, expert)
#define MEP (NG*32)           // 4096 padded rows per expert (slot 31 = zero pad)

static __device__ __forceinline__ u16 f2b(float f) {
  union { float f; unsigned u; } v; v.f = f;
  unsigned r = v.u + 0x7fffu + ((v.u >> 16) & 1u);
  return (u16)(r >> 16);
}
static __device__ __forceinline__ float b2f(u16 u) {
  union { unsigned u; float f; } v; v.u = (unsigned)u << 16; return v.f;
}

// jax.nn.gelu default = tanh approximation
static __device__ __forceinline__ float gelu_f(float x) {
  float y = 0.7978845608028654f * (x + 0.044715f * x * x * x);
  float t = __expf(-2.0f * fabsf(y));
  float th = (1.0f - t) / (1.0f + t);
  th = (y < 0.0f) ? -th : th;
  return 0.5f * x * (1.0f + th);
}

static __device__ __forceinline__ void gl2lds16(const void* g, void* l) {
  __builtin_amdgcn_global_load_lds(
      (const __attribute__((address_space(1))) void*)g,
      (__attribute__((address_space(3))) void*)l, 16, 0, 0);
}

// ---------------- router: logits (fp64 accum), softmax, top-2 ----------------
__global__ __launch_bounds__(256) void k_router(
    const float* __restrict__ x, const float* __restrict__ gw,
    const float* __restrict__ gb, int* __restrict__ e_sel,
    float* __restrict__ gsel) {
  int wave = threadIdx.x >> 6, lane = threadIdx.x & 63;
  int t = blockIdx.x * 4 + wave;
  const float* xr = x + (size_t)t * DM;
  double acc[8] = {0,0,0,0,0,0,0,0};
  for (int d0 = lane * 4; d0 < DM; d0 += 256) {
    float4 xv = *(const float4*)(xr + d0);
    float xa[4] = {xv.x, xv.y, xv.z, xv.w};
    const float* g0 = gw + (size_t)d0 * NE;
#pragma unroll
    for (int dd = 0; dd < 4; ++dd)
#pragma unroll
      for (int e = 0; e < 8; ++e)
        acc[e] += (double)xa[dd] * (double)g0[dd * 8 + e];
  }
#pragma unroll
  for (int off = 32; off > 0; off >>= 1)
#pragma unroll
    for (int e = 0; e < 8; ++e)
      acc[e] += __shfl_down(acc[e], off, 64);
  if (lane == 0) {
    float l[8];
#pragma unroll
    for (int e = 0; e < 8; ++e) l[e] = (float)acc[e] + gb[e];
    int e0 = 0;
    for (int e = 1; e < 8; ++e) if (l[e] > l[e0]) e0 = e;
    int e1 = (e0 == 0) ? 1 : 0;
    for (int e = 0; e < 8; ++e) if (e != e0 && l[e] > l[e1]) e1 = e;
    float m = l[e0], s = 0.f, p[8];
    for (int e = 0; e < 8; ++e) { p[e] = expf(l[e] - m); s += p[e]; }
    e_sel[t] = e0; e_sel[TOK + t] = e1;
    gsel[t] = p[e0] / s; gsel[TOK + t] = p[e1] / s;
  }
}

// ------------- capacity assignment: serial cumsum per group, per-k ----------
// slot id m = e*MEP + g*32 + c, c in [0,31); c==31 is permanent zero-pad.
__global__ void k_assign(const int* __restrict__ e_sel,
                         int* __restrict__ tok_slot, int* __restrict__ slot_tok) {
  int g = blockIdx.x;
  for (int i = threadIdx.x; i < NE * 32 * 2; i += 64) {
    int e = i >> 6, rem = i & 63, c = rem >> 1, k = rem & 1;
    slot_tok[((size_t)(e * MEP + g * 32 + c)) * 2 + k] = -1;
  }
  __syncthreads();
  if (threadIdx.x == 0) {
    int cnt[2][NE];
    for (int k = 0; k < 2; ++k) for (int e = 0; e < NE; ++e) cnt[k][e] = 0;
    for (int s = 0; s < GSZ; ++s) {
      int t = g * GSZ + s;
      for (int k = 0; k < 2; ++k) {
        int e = e_sel[k * TOK + t];
        int r = ++cnt[k][e];
        if (r <= CAPM) {
          int m = e * MEP + g * 32 + (r - 1);
          tok_slot[k * TOK + t] = m;
          slot_tok[(size_t)m * 2 + k] = t;
        } else tok_slot[k * TOK + t] = -1;
      }
    }
  }
}

// ------- exp_in[m,:] = bf16( x[t0] + x[t1] ); pad slots -> zeros ------------
__global__ __launch_bounds__(128) void k_build_expin(
    const float* __restrict__ x, const int* __restrict__ slot_tok,
    u16* __restrict__ exp_in) {
  int m = blockIdx.x;
  int t0 = slot_tok[(size_t)m * 2], t1 = slot_tok[(size_t)m * 2 + 1];
  int d = threadIdx.x * 8;
  float v[8] = {0,0,0,0,0,0,0,0};
  if (t0 >= 0) {
    const float4* p = (const float4*)(x + (size_t)t0 * DM + d);
    float4 a = p[0], b = p[1];
    v[0]+=a.x; v[1]+=a.y; v[2]+=a.z; v[3]+=a.w;
    v[4]+=b.x; v[5]+=b.y; v[6]+=b.z; v[7]+=b.w;
  }
  if (t1 >= 0) {
    const float4* p = (const float4*)(x + (size_t)t1 * DM + d);
    float4 a = p[0], b = p[1];
    v[0]+=a.x; v[1]+=a.y; v[2]+=a.z; v[3]+=a.w;
    v[4]+=b.x; v[5]+=b.y; v[6]+=b.z; v[7]+=b.w;
  }
  ushort4 o0, o1;
  o0.x=f2b(v[0]); o0.y=f2b(v[1]); o0.z=f2b(v[2]); o0.w=f2b(v[3]);
  o1.x=f2b(v[4]); o1.y=f2b(v[5]); o1.z=f2b(v[6]); o1.w=f2b(v[7]);
  *(ushort4*)(exp_in + (size_t)m * DM + d) = o0;
  *(ushort4*)(exp_in + (size_t)m * DM + d + 4) = o1;
}

// ------------------------------ fp32 -> bf16 --------------------------------
__global__ __launch_bounds__(256) void k_cast_bf16(
    const float* __restrict__ in, u16* __restrict__ out, size_t n) {
  size_t i = ((size_t)blockIdx.x * 256 + threadIdx.x) * 4;
  if (i >= n) return;
  float4 v = *(const float4*)(in + i);
  ushort4 o; o.x=f2b(v.x); o.y=f2b(v.y); o.z=f2b(v.z); o.w=f2b(v.w);
  *(ushort4*)(out + i) = o;
}

// --------- transpose+cast: in(k,n) at in[k*rs+n] fp32 -> out[n*K+k] bf16 ----
__global__ __launch_bounds__(256) void k_transpose(
    const float* __restrict__ in, u16* __restrict__ out,
    int K, int N, int rs) {
  __shared__ float tile[32][33];
  int k0 = blockIdx.x * 32, n0 = blockIdx.y * 32;
  int tx = threadIdx.x & 31, ty = threadIdx.x >> 5;
#pragma unroll
  for (int i = 0; i < 4; ++i)
    tile[ty + i * 8][tx] = in[(size_t)(k0 + ty + i * 8) * rs + n0 + tx];
  __syncthreads();
#pragma unroll
  for (int i = 0; i < 4; ++i) {
    int n = ty + i * 8;
    out[(size_t)(n0 + n) * K + k0 + tx] = f2b(tile[tx][n]);
  }
}

// ------------- 256x256 bf16 MFMA GEMM, C = A(MxK) * B^T(NxK) ----------------
// BK=64, 8 waves (2Mx4N), dbuf LDS + T2 XOR swizzle (slot ^= row&7),
// prefetch issued before compute, ONE barrier per K-tile, T1 XCD swizzle.
// EPI 0: bf16 gelu(acc+bias); 1: bf16 acc+bias; 2: f32 acc+bias.
static __device__ __forceinline__ void stage256(const u16* __restrict__ g, int ld,
                                                u16* lds, int tid) {
#pragma unroll
  for (int r = 0; r < 4; ++r) {
    int row = r * 64 + (tid >> 3);
    int cs = (((tid & 7) ^ (row & 7)) << 3);     // inverse-swizzled source col
    gl2lds16(g + (size_t)row * ld + cs,
             lds + (size_t)(r * 512 + (tid & ~63)) * 8);   // linear dest
  }
}

template <int EPI>
__global__ __launch_bounds__(512, 2) void k_gemm256(
    const u16* __restrict__ A, size_t sAe, int lda,
    const u16* __restrict__ B, size_t sBe, int ldb,
    void* __restrict__ Cv, size_t sCe, int ldc,
    const float* __restrict__ bias, int sBiasE, int K, int gx, int gy) {
  __shared__ __align__(16) u16 As[2][256 * 64];
  __shared__ __align__(16) u16 Bs[2][256 * 64];
  const int tid = threadIdx.x;
  const int lane = tid & 63, wid = tid >> 6;
  const int wr = wid >> 2, wc = wid & 3;         // 2 x 4 waves

  // T1: bijective XCD-chunked remap of 1D grid (gridDim.x % 8 == 0)
  int nwg = gridDim.x, per = nwg >> 3;
  int wg = (blockIdx.x & 7) * per + (blockIdx.x >> 3);
  int bx = wg % gx, tmp = wg / gx;
  int by = tmp % gy, z = tmp / gy;

  const u16* Ab = A + (size_t)z * sAe + (size_t)(bx * 256) * lda;
  const u16* Bb = B + (size_t)z * sBe + (size_t)(by * 256) * ldb;

  f32x4 acc[8][4] = {};

  const int NT = K >> 6;
  int buf = 0;
  stage256(Ab, lda, As[0], tid);
  stage256(Bb, ldb, Bs[0], tid);
  __syncthreads();

  for (int kt = 0; kt < NT; ++kt) {
    if (kt + 1 < NT) {                            // prefetch next K-tile
      stage256(Ab + (kt + 1) * 64, lda, As[buf ^ 1], tid);
      stage256(Bb + (kt + 1) * 64, ldb, Bs[buf ^ 1], tid);
    }
    const u16* Asb = As[buf];
    const u16* Bsb = Bs[buf];
#pragma unroll
    for (int kk = 0; kk < 64; kk += 32) {
      const int s0 = (kk + ((lane >> 4) << 3)) >> 3;
      bf16x8 fa[8], fb[4];
#pragma unroll
      for (int mi = 0; mi < 8; ++mi) {
        int row = wr * 128 + mi * 16 + (lane & 15);
        fa[mi] = *(const bf16x8*)(Asb + row * 64 + ((s0 ^ (row & 7)) << 3));
      }
#pragma unroll
      for (int ni = 0; ni < 4; ++ni) {
        int row = wc * 64 + ni * 16 + (lane & 15);
        fb[ni] = *(const bf16x8*)(Bsb + row * 64 + ((s0 ^ (row & 7)) << 3));
      }
      __builtin_amdgcn_s_setprio(1);
#pragma unroll
      for (int mi = 0; mi < 8; ++mi)
#pragma unroll
        for (int ni = 0; ni < 4; ++ni)
          acc[mi][ni] = __builtin_amdgcn_mfma_f32_16x16x32_bf16(fa[mi], fb[ni], acc[mi][ni], 0, 0, 0);
      __builtin_amdgcn_s_setprio(0);
    }
    __syncthreads();                              // drains vmcnt for prefetch
    buf ^= 1;
  }

  const int r0 = bx * 256 + wr * 128 + ((lane >> 4) << 2);
  const int c0 = by * 256 + wc * 64 + (lane & 15);
#pragma unroll
  for (int ni = 0; ni < 4; ++ni) {
    int col = c0 + ni * 16;
    float bv = bias[(size_t)z * sBiasE + col];
#pragma unroll
    for (int mi = 0; mi < 8; ++mi) {
      f32x4 v = acc[mi][ni];
#pragma unroll
      for (int j = 0; j < 4; ++j) {
        int row = r0 + mi * 16 + j;
        float val = v[j] + bv;
        if (EPI == 0)
          ((u16*)Cv)[(size_t)z * sCe + (size_t)row * ldc + col] = f2b(gelu_f(val));
        else if (EPI == 1)
          ((u16*)Cv)[(size_t)z * sCe + (size_t)row * ldc + col] = f2b(val);
        else
          ((float*)Cv)[(size_t)z * sCe + (size_t)row * ldc + col] = val;
      }
    }
  }
}

// ------------------ out[t] += sum_k gate_k * eo[slot_k] (eo bf16) -----------
__global__ __launch_bounds__(256) void k_combine(
    const int* __restrict__ tok_slot, const float* __restrict__ gsel,
    const u16* __restrict__ eo, float* __restrict__ out) {
  int t = blockIdx.x;
  int d = threadIdx.x * 4;
  float4 v = *(float4*)(out + (size_t)t * DM + d);
#pragma unroll
  for (int k = 0; k < 2; ++k) {
    int m = tok_slot[k * TOK + t];
    if (m >= 0) {
      float g = gsel[k * TOK + t];
      ushort4 e = *(const ushort4*)(eo + (size_t)m * DM + d);
      v.x += g * b2f(e.x); v.y += g * b2f(e.y);
      v.z += g * b2f(e.z); v.w += g * b2f(e.w);
    }
  }
  *(float4*)(out + (size_t)t * DM + d) = v;
}

__global__ void k_report(float* out, float code) { out[0] = code; }

extern "C" void kernel_launch(void* const* d_in, const int* in_sizes, int n_in,
                              void* d_out, int out_size, void* d_ws, size_t ws_size,
                              hipStream_t stream) {
  (void)in_sizes; (void)n_in;
  const float* x     = (const float*)d_in[0];
  const float* gw    = (const float*)d_in[1];
  const float* gb    = (const float*)d_in[2];
  const float* keys  = (const float*)d_in[3];
  const float* keyb  = (const float*)d_in[4];
  const float* vals  = (const float*)d_in[5];
  const float* valb  = (const float*)d_in[6];
  const float* skey  = (const float*)d_in[7];
  const float* skeyb = (const float*)d_in[8];
  const float* sval  = (const float*)d_in[9];
  const float* svalb = (const float*)d_in[10];
  float* out = (float*)d_out;

  char* ws = (char*)d_ws;
  size_t off = 0;
  auto alloc = [&](size_t bytes) -> char* {
    char* p = ws + off; off += (bytes + 255) & ~(size_t)255; return p;
  };
  int*   e_sel    = (int*)  alloc(2 * TOK * 4);
  float* gsel     = (float*)alloc(2 * TOK * 4);
  int*   tok_slot = (int*)  alloc(2 * TOK * 4);
  int*   slot_tok = (int*)  alloc((size_t)NE * MEP * 2 * 4);

  size_t off_r1 = off;              // union: {xb,skT,svT,exp_in} then eo(bf16)
  u16* xb     = (u16*)alloc((size_t)TOK * DM * 2);
  u16* skT    = (u16*)alloc((size_t)HD * DM * 2);
  u16* svT    = (u16*)alloc((size_t)DM * HD * 2);
  u16* exp_in = (u16*)alloc((size_t)NE * MEP * DM * 2);
  u16* eo = (u16*)(ws + off_r1);
  size_t eo_end = off_r1 + (size_t)NE * MEP * DM * 2;
  if (eo_end > off) off = eo_end;

  u16* keysT = (u16*)alloc((size_t)NE * HD * DM * 2);
  u16* valsT = (u16*)alloc((size_t)NE * DM * HD * 2);

  size_t sh_b = (size_t)TOK * HD * 2;          // union: sh then h
  size_t h_b  = (size_t)NE * MEP * HD * 2;
  u16* sh = (u16*)(ws + off);
  u16* h  = (u16*)(ws + off);
  size_t need = off + (sh_b > h_b ? sh_b : h_b);

  if (need > ws_size) {                        // sentinel: out[0] = -available MB
    hipMemsetAsync(d_out, 0, (size_t)out_size * 4, stream);
    k_report<<<1, 1, 0, stream>>>(out, -(float)(ws_size >> 20));
    return;
  }

  // routing + assignment + dispatch gather
  k_router<<<TOK / 4, 256, 0, stream>>>(x, gw, gb, e_sel, gsel);
  k_assign<<<NG, 64, 0, stream>>>(e_sel, tok_slot, slot_tok);
  k_build_expin<<<NE * MEP, 128, 0, stream>>>(x, slot_tok, exp_in);

  // bf16 casts / weight transposes
  k_cast_bf16<<<(TOK * DM / 4) / 256, 256, 0, stream>>>(x, xb, (size_t)TOK * DM);
  k_transpose<<<dim3(DM / 32, HD / 32), 256, 0, stream>>>(skey, skT, DM, HD, HD);
  k_transpose<<<dim3(HD / 32, DM / 32), 256, 0, stream>>>(sval, svT, HD, DM, DM);
  for (int e = 0; e < NE; ++e) {
    k_transpose<<<dim3(DM / 32, HD / 32), 256, 0, stream>>>(
        keys + (size_t)e * HD, keysT + (size_t)e * HD * DM, DM, HD, NE * HD);
    k_transpose<<<dim3(HD / 32, DM / 32), 256, 0, stream>>>(
        vals + (size_t)e * DM, valsT + (size_t)e * DM * HD, HD, DM, NE * DM);
  }

  // shared expert: sh = gelu(xb @ skT + skeyb); out = sh @ svT + svalb
  k_gemm256<0><<<(TOK/256)*(HD/256), 512, 0, stream>>>(
      xb, 0, DM, skT, 0, DM, sh, 0, HD, skeyb, 0, DM, TOK/256, HD/256);
  k_gemm256<2><<<(TOK/256)*(DM/256), 512, 0, stream>>>(
      sh, 0, HD, svT, 0, HD, out, 0, DM, svalb, 0, HD, TOK/256, DM/256);

  // MoE experts
  k_gemm256<0><<<(MEP/256)*(HD/256)*NE, 512, 0, stream>>>(
      exp_in, (size_t)MEP * DM, DM, keysT, (size_t)HD * DM, DM,
      h, (size_t)MEP * HD, HD, keyb, HD, DM, MEP/256, HD/256);
  k_gemm256<1><<<(MEP/256)*(DM/256)*NE, 512, 0, stream>>>(
      h, (size_t)MEP * HD, HD, valsT, (size_t)DM * HD, HD,
      eo, (size_t)MEP * DM, DM, valb, DM, HD, MEP/256, DM/256);

  // combine: out += gate * eo[slot]
  k_combine<<<TOK, 256, 0, stream>>>(tok_slot, gsel, eo, out);
}

// Round 8
// 1354.271 us; speedup vs baseline: 1.3384x; 1.1389x over previous
//
#include <hip/hip_runtime.h>
#include <hip/hip_bf16.h>

typedef unsigned short u16;
typedef __attribute__((ext_vector_type(8))) __bf16 bf16x8;
typedef __attribute__((ext_vector_type(4))) float f32x4;

#define TOK 16384
#define DM  1024
#define HD  4096
#define NE  8
#define NG  128
#define GSZ 128
#define CAPM 31               // usable slots per (group, expert)
#define MEP (NG*32)           // 4096 padded rows per expert (slot 31 = zero pad)

static __device__ __forceinline__ u16 f2b(float f) {
  union { float f; unsigned u; } v; v.f = f;
  unsigned r = v.u + 0x7fffu + ((v.u >> 16) & 1u);
  return (u16)(r >> 16);
}
static __device__ __forceinline__ float b2f(u16 u) {
  union { unsigned u; float f; } v; v.u = (unsigned)u << 16; return v.f;
}

// jax.nn.gelu default = tanh approximation
static __device__ __forceinline__ float gelu_f(float x) {
  float y = 0.7978845608028654f * (x + 0.044715f * x * x * x);
  float t = __expf(-2.0f * fabsf(y));
  float th = (1.0f - t) / (1.0f + t);
  th = (y < 0.0f) ? -th : th;
  return 0.5f * x * (1.0f + th);
}

static __device__ __forceinline__ void gl2lds16(const void* g, void* l) {
  __builtin_amdgcn_global_load_lds(
      (const __attribute__((address_space(1))) void*)g,
      (__attribute__((address_space(3))) void*)l, 16, 0, 0);
}

// ---------------- router: logits (fp64 accum), softmax, top-2 ----------------
__global__ __launch_bounds__(256) void k_router(
    const float* __restrict__ x, const float* __restrict__ gw,
    const float* __restrict__ gb, int* __restrict__ e_sel,
    float* __restrict__ gsel) {
  int wave = threadIdx.x >> 6, lane = threadIdx.x & 63;
  int t = blockIdx.x * 4 + wave;
  const float* xr = x + (size_t)t * DM;
  double acc[8] = {0,0,0,0,0,0,0,0};
  for (int d0 = lane * 4; d0 < DM; d0 += 256) {
    float4 xv = *(const float4*)(xr + d0);
    float xa[4] = {xv.x, xv.y, xv.z, xv.w};
    const float* g0 = gw + (size_t)d0 * NE;
#pragma unroll
    for (int dd = 0; dd < 4; ++dd)
#pragma unroll
      for (int e = 0; e < 8; ++e)
        acc[e] += (double)xa[dd] * (double)g0[dd * 8 + e];
  }
#pragma unroll
  for (int off = 32; off > 0; off >>= 1)
#pragma unroll
    for (int e = 0; e < 8; ++e)
      acc[e] += __shfl_down(acc[e], off, 64);
  if (lane == 0) {
    float l[8];
#pragma unroll
    for (int e = 0; e < 8; ++e) l[e] = (float)acc[e] + gb[e];
    int e0 = 0;
    for (int e = 1; e < 8; ++e) if (l[e] > l[e0]) e0 = e;
    int e1 = (e0 == 0) ? 1 : 0;
    for (int e = 0; e < 8; ++e) if (e != e0 && l[e] > l[e1]) e1 = e;
    float m = l[e0], s = 0.f, p[8];
    for (int e = 0; e < 8; ++e) { p[e] = expf(l[e] - m); s += p[e]; }
    e_sel[t] = e0; e_sel[TOK + t] = e1;
    gsel[t] = p[e0] / s; gsel[TOK + t] = p[e1] / s;
  }
}

// ------------- capacity assignment: serial cumsum per group, per-k ----------
__global__ void k_assign(const int* __restrict__ e_sel,
                         int* __restrict__ tok_slot, int* __restrict__ slot_tok) {
  int g = blockIdx.x;
  for (int i = threadIdx.x; i < NE * 32 * 2; i += 64) {
    int e = i >> 6, rem = i & 63, c = rem >> 1, k = rem & 1;
    slot_tok[((size_t)(e * MEP + g * 32 + c)) * 2 + k] = -1;
  }
  __syncthreads();
  if (threadIdx.x == 0) {
    int cnt[2][NE];
    for (int k = 0; k < 2; ++k) for (int e = 0; e < NE; ++e) cnt[k][e] = 0;
    for (int s = 0; s < GSZ; ++s) {
      int t = g * GSZ + s;
      for (int k = 0; k < 2; ++k) {
        int e = e_sel[k * TOK + t];
        int r = ++cnt[k][e];
        if (r <= CAPM) {
          int m = e * MEP + g * 32 + (r - 1);
          tok_slot[k * TOK + t] = m;
          slot_tok[(size_t)m * 2 + k] = t;
        } else tok_slot[k * TOK + t] = -1;
      }
    }
  }
}

// ------- exp_in[m,:] = bf16( x[t0] + x[t1] ); pad slots -> zeros ------------
__global__ __launch_bounds__(128) void k_build_expin(
    const float* __restrict__ x, const int* __restrict__ slot_tok,
    u16* __restrict__ exp_in) {
  int m = blockIdx.x;
  int t0 = slot_tok[(size_t)m * 2], t1 = slot_tok[(size_t)m * 2 + 1];
  int d = threadIdx.x * 8;
  float v[8] = {0,0,0,0,0,0,0,0};
  if (t0 >= 0) {
    const float4* p = (const float4*)(x + (size_t)t0 * DM + d);
    float4 a = p[0], b = p[1];
    v[0]+=a.x; v[1]+=a.y; v[2]+=a.z; v[3]+=a.w;
    v[4]+=b.x; v[5]+=b.y; v[6]+=b.z; v[7]+=b.w;
  }
  if (t1 >= 0) {
    const float4* p = (const float4*)(x + (size_t)t1 * DM + d);
    float4 a = p[0], b = p[1];
    v[0]+=a.x; v[1]+=a.y; v[2]+=a.z; v[3]+=a.w;
    v[4]+=b.x; v[5]+=b.y; v[6]+=b.z; v[7]+=b.w;
  }
  ushort4 o0, o1;
  o0.x=f2b(v[0]); o0.y=f2b(v[1]); o0.z=f2b(v[2]); o0.w=f2b(v[3]);
  o1.x=f2b(v[4]); o1.y=f2b(v[5]); o1.z=f2b(v[6]); o1.w=f2b(v[7]);
  *(ushort4*)(exp_in + (size_t)m * DM + d) = o0;
  *(ushort4*)(exp_in + (size_t)m * DM + d + 4) = o1;
}

// ------------------------------ fp32 -> bf16 --------------------------------
__global__ __launch_bounds__(256) void k_cast_bf16(
    const float* __restrict__ in, u16* __restrict__ out, size_t n) {
  size_t i = ((size_t)blockIdx.x * 256 + threadIdx.x) * 4;
  if (i >= n) return;
  float4 v = *(const float4*)(in + i);
  ushort4 o; o.x=f2b(v.x); o.y=f2b(v.y); o.z=f2b(v.z); o.w=f2b(v.w);
  *(ushort4*)(out + i) = o;
}

// --------- transpose+cast: in(k,n) at in[k*rs+n] fp32 -> out[n*K+k] bf16 ----
__global__ __launch_bounds__(256) void k_transpose(
    const float* __restrict__ in, u16* __restrict__ out,
    int K, int N, int rs) {
  __shared__ float tile[32][33];
  int k0 = blockIdx.x * 32, n0 = blockIdx.y * 32;
  int tx = threadIdx.x & 31, ty = threadIdx.x >> 5;
#pragma unroll
  for (int i = 0; i < 4; ++i)
    tile[ty + i * 8][tx] = in[(size_t)(k0 + ty + i * 8) * rs + n0 + tx];
  __syncthreads();
#pragma unroll
  for (int i = 0; i < 4; ++i) {
    int n = ty + i * 8;
    out[(size_t)(n0 + n) * K + k0 + tx] = f2b(tile[tx][n]);
  }
}

// ---- 256x256 bf16 MFMA GEMM, 8-phase counted-vmcnt schedule (T2+T3+T4+T5) --
// C = A(MxK) * B^T(NxK). BK=64, 8 waves, STRIDED wave tiling:
//   A-frag row = (mi*2+wr)*16, B-frag row = (ni*4+wc)*16  -> halves are
//   phase-sequential across all waves. LDS = 4-slot ring of 128x64 halves
//   per matrix (128 KiB). Per K-tile: 4 phases, each {ds_read ∥ stage one
//   half of t+1 -> bar -> lgkm0 -> prio1 -> 16 MFMA -> prio0 -> vmcnt(4) -> bar}.
// Stage order [Ah0,Bh0,Bh1,Ah1]: each vmcnt(4) forces the just-in-time half
// (ledger-verified, >=3-phase lead). vmcnt never drains to 0 in the loop.
static __device__ __forceinline__ void stg_half(const u16* __restrict__ g, int ld,
                                                u16* lds, int tid) {
#pragma unroll
  for (int i = 0; i < 2; ++i) {
    int r = i * 64 + (tid >> 3);
    int cs = (((tid & 7) ^ (r & 7)) << 3);       // inverse-swizzled source col
    gl2lds16(g + (size_t)r * ld + cs,
             lds + (size_t)i * 4096 + (size_t)(tid & ~63) * 8);  // linear dest
  }
}

#define PH_MID() \
  __builtin_amdgcn_s_barrier(); \
  asm volatile("s_waitcnt lgkmcnt(0)" ::: "memory"); \
  __builtin_amdgcn_sched_barrier(0); \
  __builtin_amdgcn_s_setprio(1);

#define PH_END() \
  __builtin_amdgcn_s_setprio(0); \
  asm volatile("s_waitcnt vmcnt(4)" ::: "memory"); \
  __builtin_amdgcn_s_barrier();

template <int EPI>
__global__ __launch_bounds__(512, 2) void k_gemm8p(
    const u16* __restrict__ A, size_t sAe, int lda,
    const u16* __restrict__ B, size_t sBe, int ldb,
    void* __restrict__ Cv, size_t sCe, int ldc,
    const float* __restrict__ bias, int sBiasE, int K, int gx, int gy) {
  __shared__ __align__(16) u16 HA[4][128 * 64];
  __shared__ __align__(16) u16 HB[4][128 * 64];
  const int tid = threadIdx.x;
  const int lane = tid & 63, wid = tid >> 6;
  const int wr = wid >> 2, wc = wid & 3;
  const int la15 = lane & 15, hi = lane >> 4;

  // T1: bijective XCD-chunked remap of 1D grid (gridDim.x % 8 == 0)
  int nwg = gridDim.x, per = nwg >> 3;
  int wg = (blockIdx.x & 7) * per + (blockIdx.x >> 3);
  int bx = wg % gx, tmp = wg / gx;
  int by = tmp % gy, z = tmp / gy;

  const u16* Ab = A + (size_t)z * sAe + (size_t)(bx * 256) * lda;
  const u16* Bb = B + (size_t)z * sBe + (size_t)(by * 256) * ldb;

  f32x4 acc[8][4] = {};
  const int NT = K >> 6;

  // prologue: tile 0 halves, full drain once
  stg_half(Ab, lda, HA[0], tid);
  stg_half(Bb, ldb, HB[0], tid);
  stg_half(Bb + (size_t)128 * ldb, ldb, HB[1], tid);
  stg_half(Ab + (size_t)128 * lda, lda, HA[1], tid);
  asm volatile("s_waitcnt vmcnt(0)" ::: "memory");
  __builtin_amdgcn_s_barrier();

  for (int t = 0; t < NT; ++t) {
    const int s0 = (2 * t) & 3, s1 = s0 + 1;
    const int d0 = s0 ^ 2, d1 = s1 ^ 2;
    const u16* Ah0 = HA[s0]; const u16* Ah1 = HA[s1];
    const u16* Bh0 = HB[s0]; const u16* Bh1 = HB[s1];
    const bool pre = (t + 1 < NT);
    const u16* An = Ab + (t + 1) * 64;
    const u16* Bn = Bb + (t + 1) * 64;

    bf16x8 a[2][4], bA[2][2], bB[2][2];

    // ---- P0: read aL(mh0)+bA(nh0); stage A(t+1)h0; MFMA -> acc[0..3][0..1]
#pragma unroll
    for (int k2 = 0; k2 < 2; ++k2) {
      int sl = k2 * 4 + hi;
#pragma unroll
      for (int mi = 0; mi < 4; ++mi) {
        int r = (mi * 2 + wr) * 16 + la15;
        a[k2][mi] = *(const bf16x8*)(Ah0 + r * 64 + ((sl ^ (r & 7)) << 3));
      }
#pragma unroll
      for (int ni = 0; ni < 2; ++ni) {
        int r = (ni * 4 + wc) * 16 + la15;
        bA[k2][ni] = *(const bf16x8*)(Bh0 + r * 64 + ((sl ^ (r & 7)) << 3));
      }
    }
    if (pre) stg_half(An, lda, HA[d0], tid);
    PH_MID();
#pragma unroll
    for (int k2 = 0; k2 < 2; ++k2)
#pragma unroll
      for (int mi = 0; mi < 4; ++mi)
#pragma unroll
        for (int ni = 0; ni < 2; ++ni)
          acc[mi][ni] = __builtin_amdgcn_mfma_f32_16x16x32_bf16(
              a[k2][mi], bA[k2][ni], acc[mi][ni], 0, 0, 0);
    PH_END();

    // ---- P1: read bB(nh1); stage B(t+1)h0; MFMA -> acc[0..3][2..3]
#pragma unroll
    for (int k2 = 0; k2 < 2; ++k2) {
      int sl = k2 * 4 + hi;
#pragma unroll
      for (int ni = 0; ni < 2; ++ni) {
        int r = (ni * 4 + wc) * 16 + la15;
        bB[k2][ni] = *(const bf16x8*)(Bh1 + r * 64 + ((sl ^ (r & 7)) << 3));
      }
    }
    if (pre) stg_half(Bn, ldb, HB[d0], tid);
    PH_MID();
#pragma unroll
    for (int k2 = 0; k2 < 2; ++k2)
#pragma unroll
      for (int mi = 0; mi < 4; ++mi)
#pragma unroll
        for (int ni = 0; ni < 2; ++ni)
          acc[mi][ni + 2] = __builtin_amdgcn_mfma_f32_16x16x32_bf16(
              a[k2][mi], bB[k2][ni], acc[mi][ni + 2], 0, 0, 0);
    PH_END();

    // ---- P2: read aH(mh1) (overwrite a); stage B(t+1)h1; MFMA -> acc[4..7][2..3]
#pragma unroll
    for (int k2 = 0; k2 < 2; ++k2) {
      int sl = k2 * 4 + hi;
#pragma unroll
      for (int mi = 0; mi < 4; ++mi) {
        int r = (mi * 2 + wr) * 16 + la15;
        a[k2][mi] = *(const bf16x8*)(Ah1 + r * 64 + ((sl ^ (r & 7)) << 3));
      }
    }
    if (pre) stg_half(Bn + (size_t)128 * ldb, ldb, HB[d1], tid);
    PH_MID();
#pragma unroll
    for (int k2 = 0; k2 < 2; ++k2)
#pragma unroll
      for (int mi = 0; mi < 4; ++mi)
#pragma unroll
        for (int ni = 0; ni < 2; ++ni)
          acc[mi + 4][ni + 2] = __builtin_amdgcn_mfma_f32_16x16x32_bf16(
              a[k2][mi], bB[k2][ni], acc[mi + 4][ni + 2], 0, 0, 0);
    PH_END();

    // ---- P3: no reads (bA live from P0); stage A(t+1)h1; MFMA -> acc[4..7][0..1]
    if (pre) stg_half(An + (size_t)128 * lda, lda, HA[d1], tid);
    PH_MID();
#pragma unroll
    for (int k2 = 0; k2 < 2; ++k2)
#pragma unroll
      for (int mi = 0; mi < 4; ++mi)
#pragma unroll
        for (int ni = 0; ni < 2; ++ni)
          acc[mi + 4][ni] = __builtin_amdgcn_mfma_f32_16x16x32_bf16(
              a[k2][mi], bA[k2][ni], acc[mi + 4][ni], 0, 0, 0);
    PH_END();
  }

  // epilogue (strided mapping)
  const int hi4 = hi << 2;
#pragma unroll
  for (int ni = 0; ni < 4; ++ni) {
    int col = by * 256 + (ni * 4 + wc) * 16 + la15;
    float bv = bias[(size_t)z * sBiasE + col];
#pragma unroll
    for (int mi = 0; mi < 8; ++mi) {
      int row0 = bx * 256 + (mi * 2 + wr) * 16 + hi4;
      f32x4 v = acc[mi][ni];
#pragma unroll
      for (int j = 0; j < 4; ++j) {
        int row = row0 + j;
        float val = v[j] + bv;
        if (EPI == 0)
          ((u16*)Cv)[(size_t)z * sCe + (size_t)row * ldc + col] = f2b(gelu_f(val));
        else if (EPI == 1)
          ((u16*)Cv)[(size_t)z * sCe + (size_t)row * ldc + col] = f2b(val);
        else
          ((float*)Cv)[(size_t)z * sCe + (size_t)row * ldc + col] = val;
      }
    }
  }
}

// ------------------ out[t] += sum_k gate_k * eo[slot_k] (eo bf16) -----------
__global__ __launch_bounds__(256) void k_combine(
    const int* __restrict__ tok_slot, const float* __restrict__ gsel,
    const u16* __restrict__ eo, float* __restrict__ out) {
  int t = blockIdx.x;
  int d = threadIdx.x * 4;
  float4 v = *(float4*)(out + (size_t)t * DM + d);
#pragma unroll
  for (int k = 0; k < 2; ++k) {
    int m = tok_slot[k * TOK + t];
    if (m >= 0) {
      float g = gsel[k * TOK + t];
      ushort4 e = *(const ushort4*)(eo + (size_t)m * DM + d);
      v.x += g * b2f(e.x); v.y += g * b2f(e.y);
      v.z += g * b2f(e.z); v.w += g * b2f(e.w);
    }
  }
  *(float4*)(out + (size_t)t * DM + d) = v;
}

__global__ void k_report(float* out, float code) { out[0] = code; }

extern "C" void kernel_launch(void* const* d_in, const int* in_sizes, int n_in,
                              void* d_out, int out_size, void* d_ws, size_t ws_size,
                              hipStream_t stream) {
  (void)in_sizes; (void)n_in;
  const float* x     = (const float*)d_in[0];
  const float* gw    = (const float*)d_in[1];
  const float* gb    = (const float*)d_in[2];
  const float* keys  = (const float*)d_in[3];
  const float* keyb  = (const float*)d_in[4];
  const float* vals  = (const float*)d_in[5];
  const float* valb  = (const float*)d_in[6];
  const float* skey  = (const float*)d_in[7];
  const float* skeyb = (const float*)d_in[8];
  const float* sval  = (const float*)d_in[9];
  const float* svalb = (const float*)d_in[10];
  float* out = (float*)d_out;

  char* ws = (char*)d_ws;
  size_t off = 0;
  auto alloc = [&](size_t bytes) -> char* {
    char* p = ws + off; off += (bytes + 255) & ~(size_t)255; return p;
  };
  int*   e_sel    = (int*)  alloc(2 * TOK * 4);
  float* gsel     = (float*)alloc(2 * TOK * 4);
  int*   tok_slot = (int*)  alloc(2 * TOK * 4);
  int*   slot_tok = (int*)  alloc((size_t)NE * MEP * 2 * 4);

  size_t off_r1 = off;              // union: {xb,skT,svT,exp_in} then eo(bf16)
  u16* xb     = (u16*)alloc((size_t)TOK * DM * 2);
  u16* skT    = (u16*)alloc((size_t)HD * DM * 2);
  u16* svT    = (u16*)alloc((size_t)DM * HD * 2);
  u16* exp_in = (u16*)alloc((size_t)NE * MEP * DM * 2);
  u16* eo = (u16*)(ws + off_r1);
  size_t eo_end = off_r1 + (size_t)NE * MEP * DM * 2;
  if (eo_end > off) off = eo_end;

  u16* keysT = (u16*)alloc((size_t)NE * HD * DM * 2);
  u16* valsT = (u16*)alloc((size_t)NE * DM * HD * 2);

  size_t sh_b = (size_t)TOK * HD * 2;          // union: sh then h
  size_t h_b  = (size_t)NE * MEP * HD * 2;
  u16* sh = (u16*)(ws + off);
  u16* h  = (u16*)(ws + off);
  size_t need = off + (sh_b > h_b ? sh_b : h_b);

  if (need > ws_size) {                        // sentinel: out[0] = -available MB
    hipMemsetAsync(d_out, 0, (size_t)out_size * 4, stream);
    k_report<<<1, 1, 0, stream>>>(out, -(float)(ws_size >> 20));
    return;
  }

  // routing + assignment + dispatch gather
  k_router<<<TOK / 4, 256, 0, stream>>>(x, gw, gb, e_sel, gsel);
  k_assign<<<NG, 64, 0, stream>>>(e_sel, tok_slot, slot_tok);
  k_build_expin<<<NE * MEP, 128, 0, stream>>>(x, slot_tok, exp_in);

  // bf16 casts / weight transposes
  k_cast_bf16<<<(TOK * DM / 4) / 256, 256, 0, stream>>>(x, xb, (size_t)TOK * DM);
  k_transpose<<<dim3(DM / 32, HD / 32), 256, 0, stream>>>(skey, skT, DM, HD, HD);
  k_transpose<<<dim3(HD / 32, DM / 32), 256, 0, stream>>>(sval, svT, HD, DM, DM);
  for (int e = 0; e < NE; ++e) {
    k_transpose<<<dim3(DM / 32, HD / 32), 256, 0, stream>>>(
        keys + (size_t)e * HD, keysT + (size_t)e * HD * DM, DM, HD, NE * HD);
    k_transpose<<<dim3(HD / 32, DM / 32), 256, 0, stream>>>(
        vals + (size_t)e * DM, valsT + (size_t)e * DM * HD, HD, DM, NE * DM);
  }

  // shared expert: sh = gelu(xb @ skT + skeyb); out = sh @ svT + svalb
  k_gemm8p<0><<<(TOK/256)*(HD/256), 512, 0, stream>>>(
      xb, 0, DM, skT, 0, DM, sh, 0, HD, skeyb, 0, DM, TOK/256, HD/256);
  k_gemm8p<2><<<(TOK/256)*(DM/256), 512, 0, stream>>>(
      sh, 0, HD, svT, 0, HD, out, 0, DM, svalb, 0, HD, TOK/256, DM/256);

  // MoE experts
  k_gemm8p<0><<<(MEP/256)*(HD/256)*NE, 512, 0, stream>>>(
      exp_in, (size_t)MEP * DM, DM, keysT, (size_t)HD * DM, DM,
      h, (size_t)MEP * HD, HD, keyb, HD, DM, MEP/256, HD/256);
  k_gemm8p<1><<<(MEP/256)*(DM/256)*NE, 512, 0, stream>>>(
      h, (size_t)MEP * HD, HD, valsT, (size_t)DM * HD, HD,
      eo, (size_t)MEP * DM, DM, valb, DM, HD, MEP/256, DM/256);

  // combine: out += gate * eo[slot]
  k_combine<<<TOK, 256, 0, stream>>>(tok_slot, gsel, eo, out);
}

// Round 9
// 1243.946 us; speedup vs baseline: 1.4571x; 1.0887x over previous
//
#include <hip/hip_runtime.h>
#include <hip/hip_bf16.h>

typedef unsigned short u16;
typedef __attribute__((ext_vector_type(8))) __bf16 bf16x8;
typedef __attribute__((ext_vector_type(4))) float f32x4;

#define TOK 16384
#define DM  1024
#define HD  4096
#define NE  8
#define NG  128
#define GSZ 128
#define CAPM 31               // usable slots per (group, expert)
#define MEP (NG*32)           // 4096 padded rows per expert (slot 31 = zero pad)

static __device__ __forceinline__ u16 f2b(float f) {
  union { float f; unsigned u; } v; v.f = f;
  unsigned r = v.u + 0x7fffu + ((v.u >> 16) & 1u);
  return (u16)(r >> 16);
}
static __device__ __forceinline__ float b2f(u16 u) {
  union { unsigned u; float f; } v; v.u = (unsigned)u << 16; return v.f;
}

// jax.nn.gelu default = tanh approximation
static __device__ __forceinline__ float gelu_f(float x) {
  float y = 0.7978845608028654f * (x + 0.044715f * x * x * x);
  float t = __expf(-2.0f * fabsf(y));
  float th = (1.0f - t) / (1.0f + t);
  th = (y < 0.0f) ? -th : th;
  return 0.5f * x * (1.0f + th);
}

static __device__ __forceinline__ void gl2lds16(const void* g, void* l) {
  __builtin_amdgcn_global_load_lds(
      (const __attribute__((address_space(1))) void*)g,
      (__attribute__((address_space(3))) void*)l, 16, 0, 0);
}

// ---------------- router: logits (fp64 accum), softmax, top-2 ----------------
__global__ __launch_bounds__(256) void k_router(
    const float* __restrict__ x, const float* __restrict__ gw,
    const float* __restrict__ gb, int* __restrict__ e_sel,
    float* __restrict__ gsel) {
  int wave = threadIdx.x >> 6, lane = threadIdx.x & 63;
  int t = blockIdx.x * 4 + wave;
  const float* xr = x + (size_t)t * DM;
  double acc[8] = {0,0,0,0,0,0,0,0};
  for (int d0 = lane * 4; d0 < DM; d0 += 256) {
    float4 xv = *(const float4*)(xr + d0);
    float xa[4] = {xv.x, xv.y, xv.z, xv.w};
    const float* g0 = gw + (size_t)d0 * NE;
#pragma unroll
    for (int dd = 0; dd < 4; ++dd)
#pragma unroll
      for (int e = 0; e < 8; ++e)
        acc[e] += (double)xa[dd] * (double)g0[dd * 8 + e];
  }
#pragma unroll
  for (int off = 32; off > 0; off >>= 1)
#pragma unroll
    for (int e = 0; e < 8; ++e)
      acc[e] += __shfl_down(acc[e], off, 64);
  if (lane == 0) {
    float l[8];
#pragma unroll
    for (int e = 0; e < 8; ++e) l[e] = (float)acc[e] + gb[e];
    int e0 = 0;
    for (int e = 1; e < 8; ++e) if (l[e] > l[e0]) e0 = e;
    int e1 = (e0 == 0) ? 1 : 0;
    for (int e = 0; e < 8; ++e) if (e != e0 && l[e] > l[e1]) e1 = e;
    float m = l[e0], s = 0.f, p[8];
    for (int e = 0; e < 8; ++e) { p[e] = expf(l[e] - m); s += p[e]; }
    e_sel[t] = e0; e_sel[TOK + t] = e1;
    gsel[t] = p[e0] / s; gsel[TOK + t] = p[e1] / s;
  }
}

// ------------- capacity assignment: serial cumsum per group, per-k ----------
__global__ void k_assign(const int* __restrict__ e_sel,
                         int* __restrict__ tok_slot, int* __restrict__ slot_tok) {
  int g = blockIdx.x;
  for (int i = threadIdx.x; i < NE * 32 * 2; i += 64) {
    int e = i >> 6, rem = i & 63, c = rem >> 1, k = rem & 1;
    slot_tok[((size_t)(e * MEP + g * 32 + c)) * 2 + k] = -1;
  }
  __syncthreads();
  if (threadIdx.x == 0) {
    int cnt[2][NE];
    for (int k = 0; k < 2; ++k) for (int e = 0; e < NE; ++e) cnt[k][e] = 0;
    for (int s = 0; s < GSZ; ++s) {
      int t = g * GSZ + s;
      for (int k = 0; k < 2; ++k) {
        int e = e_sel[k * TOK + t];
        int r = ++cnt[k][e];
        if (r <= CAPM) {
          int m = e * MEP + g * 32 + (r - 1);
          tok_slot[k * TOK + t] = m;
          slot_tok[(size_t)m * 2 + k] = t;
        } else tok_slot[k * TOK + t] = -1;
      }
    }
  }
}

// ------- exp_in[m,:] = bf16( x[t0] + x[t1] ); pad slots -> zeros ------------
__global__ __launch_bounds__(128) void k_build_expin(
    const float* __restrict__ x, const int* __restrict__ slot_tok,
    u16* __restrict__ exp_in) {
  int m = blockIdx.x;
  int t0 = slot_tok[(size_t)m * 2], t1 = slot_tok[(size_t)m * 2 + 1];
  int d = threadIdx.x * 8;
  float v[8] = {0,0,0,0,0,0,0,0};
  if (t0 >= 0) {
    const float4* p = (const float4*)(x + (size_t)t0 * DM + d);
    float4 a = p[0], b = p[1];
    v[0]+=a.x; v[1]+=a.y; v[2]+=a.z; v[3]+=a.w;
    v[4]+=b.x; v[5]+=b.y; v[6]+=b.z; v[7]+=b.w;
  }
  if (t1 >= 0) {
    const float4* p = (const float4*)(x + (size_t)t1 * DM + d);
    float4 a = p[0], b = p[1];
    v[0]+=a.x; v[1]+=a.y; v[2]+=a.z; v[3]+=a.w;
    v[4]+=b.x; v[5]+=b.y; v[6]+=b.z; v[7]+=b.w;
  }
  ushort4 o0, o1;
  o0.x=f2b(v[0]); o0.y=f2b(v[1]); o0.z=f2b(v[2]); o0.w=f2b(v[3]);
  o1.x=f2b(v[4]); o1.y=f2b(v[5]); o1.z=f2b(v[6]); o1.w=f2b(v[7]);
  *(ushort4*)(exp_in + (size_t)m * DM + d) = o0;
  *(ushort4*)(exp_in + (size_t)m * DM + d + 4) = o1;
}

// ------------------------------ fp32 -> bf16 --------------------------------
__global__ __launch_bounds__(256) void k_cast_bf16(
    const float* __restrict__ in, u16* __restrict__ out, size_t n) {
  size_t i = ((size_t)blockIdx.x * 256 + threadIdx.x) * 4;
  if (i >= n) return;
  float4 v = *(const float4*)(in + i);
  ushort4 o; o.x=f2b(v.x); o.y=f2b(v.y); o.z=f2b(v.z); o.w=f2b(v.w);
  *(ushort4*)(out + i) = o;
}

// --------- transpose+cast: in(k,n) at in[k*rs+n] fp32 -> out[n*K+k] bf16 ----
__global__ __launch_bounds__(256) void k_transpose(
    const float* __restrict__ in, u16* __restrict__ out,
    int K, int N, int rs) {
  __shared__ float tile[32][33];
  int k0 = blockIdx.x * 32, n0 = blockIdx.y * 32;
  int tx = threadIdx.x & 31, ty = threadIdx.x >> 5;
#pragma unroll
  for (int i = 0; i < 4; ++i)
    tile[ty + i * 8][tx] = in[(size_t)(k0 + ty + i * 8) * rs + n0 + tx];
  __syncthreads();
#pragma unroll
  for (int i = 0; i < 4; ++i) {
    int n = ty + i * 8;
    out[(size_t)(n0 + n) * K + k0 + tx] = f2b(tile[tx][n]);
  }
}

// ---- 256x256 bf16 MFMA GEMM, 8-phase counted-vmcnt schedule (T2+T3+T4+T5) --
// Same phase/ledger structure as round 8 (verified), with:
//  - no lgkmcnt(0)/sched_barrier: compiler emits fine-grained lgkmcnt(N) so
//    each wave's MFMA overlaps its own LDS drain.
//  - K-loop unrolled x2 -> LDS ring slots are compile-time constants.
//  - all swizzled read/stage offsets precomputed per-lane (VALU cut).
//  - peeled last tile ends with vmcnt(0) (closes end-game forcing hole).

#define PH_MID() \
  __builtin_amdgcn_s_barrier(); \
  __builtin_amdgcn_s_setprio(1);

#define PH_END() \
  __builtin_amdgcn_s_setprio(0); \
  asm volatile("s_waitcnt vmcnt(4)" ::: "memory"); \
  __builtin_amdgcn_s_barrier();

#define PH_END0() \
  __builtin_amdgcn_s_setprio(0); \
  asm volatile("s_waitcnt vmcnt(0)" ::: "memory"); \
  __builtin_amdgcn_s_barrier();

#define PH_ENDN() \
  __builtin_amdgcn_s_setprio(0); \
  __builtin_amdgcn_s_barrier();

#define STG(gp, ld, lds) \
  gl2lds16((gp) + (size_t)srow * (ld) + scol, (lds) + sdst); \
  gl2lds16((gp) + (size_t)(srow + 64) * (ld) + scol, (lds) + 4096 + sdst);

#define RD_A(SLOT) \
  _Pragma("unroll") for (int k2 = 0; k2 < 2; ++k2) \
    _Pragma("unroll") for (int mi = 0; mi < 4; ++mi) \
      a[k2][mi] = *(const bf16x8*)(&HA[SLOT][0] + offA[k2][mi]);

#define RD_BA(SLOT) \
  _Pragma("unroll") for (int k2 = 0; k2 < 2; ++k2) \
    _Pragma("unroll") for (int ni = 0; ni < 2; ++ni) \
      bA[k2][ni] = *(const bf16x8*)(&HB[SLOT][0] + offB[k2][ni]);

#define RD_BB(SLOT) \
  _Pragma("unroll") for (int k2 = 0; k2 < 2; ++k2) \
    _Pragma("unroll") for (int ni = 0; ni < 2; ++ni) \
      bB[k2][ni] = *(const bf16x8*)(&HB[SLOT][0] + offB[k2][ni]);

#define MM(BM, MOFF, NOFF) \
  _Pragma("unroll") for (int k2 = 0; k2 < 2; ++k2) \
    _Pragma("unroll") for (int mi = 0; mi < 4; ++mi) \
      _Pragma("unroll") for (int ni = 0; ni < 2; ++ni) \
        acc[mi + MOFF][ni + NOFF] = __builtin_amdgcn_mfma_f32_16x16x32_bf16( \
            a[k2][mi], BM[k2][ni], acc[mi + MOFF][ni + NOFF], 0, 0, 0);

// full tile with staging of tile T+1 (slots constant via macro args)
#define TILE(T, SA0, SA1, SB0, SB1, DA0, DA1, DB0, DB1) { \
  const u16* An = Ab + ((T) + 1) * 64; \
  const u16* Bn = Bb + ((T) + 1) * 64; \
  RD_A(SA0); RD_BA(SB0); \
  STG(An, lda, &HA[DA0][0]); \
  PH_MID(); MM(bA, 0, 0); PH_END(); \
  RD_BB(SB1); \
  STG(Bn, ldb, &HB[DB0][0]); \
  PH_MID(); MM(bB, 0, 2); PH_END(); \
  RD_A(SA1); \
  STG(Bn + (size_t)128 * ldb, ldb, &HB[DB1][0]); \
  PH_MID(); MM(bB, 4, 2); PH_END(); \
  STG(An + (size_t)128 * lda, lda, &HA[DA1][0]); \
  PH_MID(); MM(bA, 4, 0); PH_END(); \
}

// last tile: nothing staged; P0 drains vmcnt fully (guarantees its halves)
#define TILE_LAST(SA0, SA1, SB0, SB1) { \
  RD_A(SA0); RD_BA(SB0); \
  PH_MID(); MM(bA, 0, 0); PH_END0(); \
  RD_BB(SB1); \
  PH_MID(); MM(bB, 0, 2); PH_ENDN(); \
  RD_A(SA1); \
  PH_MID(); MM(bB, 4, 2); PH_ENDN(); \
  PH_MID(); MM(bA, 4, 0); PH_ENDN(); \
}

template <int EPI>
__global__ __launch_bounds__(512, 2) void k_gemm8p(
    const u16* __restrict__ A, size_t sAe, int lda,
    const u16* __restrict__ B, size_t sBe, int ldb,
    void* __restrict__ Cv, size_t sCe, int ldc,
    const float* __restrict__ bias, int sBiasE, int K, int gx, int gy) {
  __shared__ __align__(16) u16 HA[4][128 * 64];
  __shared__ __align__(16) u16 HB[4][128 * 64];
  const int tid = threadIdx.x;
  const int lane = tid & 63, wid = tid >> 6;
  const int wr = wid >> 2, wc = wid & 3;
  const int la15 = lane & 15, hi = lane >> 4;

  // T1: bijective XCD-chunked remap of 1D grid (gridDim.x % 8 == 0)
  int nwg = gridDim.x, per = nwg >> 3;
  int wg = (blockIdx.x & 7) * per + (blockIdx.x >> 3);
  int bx = wg % gx, tmp = wg / gx;
  int by = tmp % gy, z = tmp / gy;

  const u16* Ab = A + (size_t)z * sAe + (size_t)(bx * 256) * lda;
  const u16* Bb = B + (size_t)z * sBe + (size_t)(by * 256) * ldb;

  // per-lane ds_read element offsets (identical for every ring slot)
  int offA[2][4], offB[2][2];
#pragma unroll
  for (int k2 = 0; k2 < 2; ++k2) {
    int sl = k2 * 4 + hi;
#pragma unroll
    for (int mi = 0; mi < 4; ++mi) {
      int r = (mi * 2 + wr) * 16 + la15;
      offA[k2][mi] = r * 64 + ((sl ^ (r & 7)) << 3);
    }
#pragma unroll
    for (int ni = 0; ni < 2; ++ni) {
      int r = (ni * 4 + wc) * 16 + la15;
      offB[k2][ni] = r * 64 + ((sl ^ (r & 7)) << 3);
    }
  }
  // per-lane stage offsets (inverse-swizzled global src, linear LDS dest)
  const int srow = tid >> 3;
  const int scol = (((tid & 7) ^ (srow & 7)) << 3);
  const int sdst = (tid & ~63) * 8;

  f32x4 acc[8][4] = {};
  const int NT = K >> 6;

  bf16x8 a[2][4], bA[2][2], bB[2][2];

  // prologue: tile 0 (4 halves), full drain once
  STG(Ab, lda, &HA[0][0]);
  STG(Bb, ldb, &HB[0][0]);
  STG(Bb + (size_t)128 * ldb, ldb, &HB[1][0]);
  STG(Ab + (size_t)128 * lda, lda, &HA[1][0]);
  asm volatile("s_waitcnt vmcnt(0)" ::: "memory");
  __builtin_amdgcn_s_barrier();

  for (int t = 0; t + 2 < NT; t += 2) {
    TILE(t,     0, 1, 0, 1, 2, 3, 2, 3);
    TILE(t + 1, 2, 3, 2, 3, 0, 1, 0, 1);
  }
  TILE(NT - 2, 0, 1, 0, 1, 2, 3, 2, 3);
  TILE_LAST(2, 3, 2, 3);

  // epilogue (strided mapping)
  const int hi4 = hi << 2;
#pragma unroll
  for (int ni = 0; ni < 4; ++ni) {
    int col = by * 256 + (ni * 4 + wc) * 16 + la15;
    float bv = bias[(size_t)z * sBiasE + col];
#pragma unroll
    for (int mi = 0; mi < 8; ++mi) {
      int row0 = bx * 256 + (mi * 2 + wr) * 16 + hi4;
      f32x4 v = acc[mi][ni];
#pragma unroll
      for (int j = 0; j < 4; ++j) {
        int row = row0 + j;
        float val = v[j] + bv;
        if (EPI == 0)
          ((u16*)Cv)[(size_t)z * sCe + (size_t)row * ldc + col] = f2b(gelu_f(val));
        else if (EPI == 1)
          ((u16*)Cv)[(size_t)z * sCe + (size_t)row * ldc + col] = f2b(val);
        else
          ((float*)Cv)[(size_t)z * sCe + (size_t)row * ldc + col] = val;
      }
    }
  }
}

// ------------------ out[t] += sum_k gate_k * eo[slot_k] (eo bf16) -----------
__global__ __launch_bounds__(256) void k_combine(
    const int* __restrict__ tok_slot, const float* __restrict__ gsel,
    const u16* __restrict__ eo, float* __restrict__ out) {
  int t = blockIdx.x;
  int d = threadIdx.x * 4;
  float4 v = *(float4*)(out + (size_t)t * DM + d);
#pragma unroll
  for (int k = 0; k < 2; ++k) {
    int m = tok_slot[k * TOK + t];
    if (m >= 0) {
      float g = gsel[k * TOK + t];
      ushort4 e = *(const ushort4*)(eo + (size_t)m * DM + d);
      v.x += g * b2f(e.x); v.y += g * b2f(e.y);
      v.z += g * b2f(e.z); v.w += g * b2f(e.w);
    }
  }
  *(float4*)(out + (size_t)t * DM + d) = v;
}

__global__ void k_report(float* out, float code) { out[0] = code; }

extern "C" void kernel_launch(void* const* d_in, const int* in_sizes, int n_in,
                              void* d_out, int out_size, void* d_ws, size_t ws_size,
                              hipStream_t stream) {
  (void)in_sizes; (void)n_in;
  const float* x     = (const float*)d_in[0];
  const float* gw    = (const float*)d_in[1];
  const float* gb    = (const float*)d_in[2];
  const float* keys  = (const float*)d_in[3];
  const float* keyb  = (const float*)d_in[4];
  const float* vals  = (const float*)d_in[5];
  const float* valb  = (const float*)d_in[6];
  const float* skey  = (const float*)d_in[7];
  const float* skeyb = (const float*)d_in[8];
  const float* sval  = (const float*)d_in[9];
  const float* svalb = (const float*)d_in[10];
  float* out = (float*)d_out;

  char* ws = (char*)d_ws;
  size_t off = 0;
  auto alloc = [&](size_t bytes) -> char* {
    char* p = ws + off; off += (bytes + 255) & ~(size_t)255; return p;
  };
  int*   e_sel    = (int*)  alloc(2 * TOK * 4);
  float* gsel     = (float*)alloc(2 * TOK * 4);
  int*   tok_slot = (int*)  alloc(2 * TOK * 4);
  int*   slot_tok = (int*)  alloc((size_t)NE * MEP * 2 * 4);

  size_t off_r1 = off;              // union: {xb,skT,svT,exp_in} then eo(bf16)
  u16* xb     = (u16*)alloc((size_t)TOK * DM * 2);
  u16* skT    = (u16*)alloc((size_t)HD * DM * 2);
  u16* svT    = (u16*)alloc((size_t)DM * HD * 2);
  u16* exp_in = (u16*)alloc((size_t)NE * MEP * DM * 2);
  u16* eo = (u16*)(ws + off_r1);
  size_t eo_end = off_r1 + (size_t)NE * MEP * DM * 2;
  if (eo_end > off) off = eo_end;

  u16* keysT = (u16*)alloc((size_t)NE * HD * DM * 2);
  u16* valsT = (u16*)alloc((size_t)NE * DM * HD * 2);

  size_t sh_b = (size_t)TOK * HD * 2;          // union: sh then h
  size_t h_b  = (size_t)NE * MEP * HD * 2;
  u16* sh = (u16*)(ws + off);
  u16* h  = (u16*)(ws + off);
  size_t need = off + (sh_b > h_b ? sh_b : h_b);

  if (need > ws_size) {                        // sentinel: out[0] = -available MB
    hipMemsetAsync(d_out, 0, (size_t)out_size * 4, stream);
    k_report<<<1, 1, 0, stream>>>(out, -(float)(ws_size >> 20));
    return;
  }

  // routing + assignment + dispatch gather
  k_router<<<TOK / 4, 256, 0, stream>>>(x, gw, gb, e_sel, gsel);
  k_assign<<<NG, 64, 0, stream>>>(e_sel, tok_slot, slot_tok);
  k_build_expin<<<NE * MEP, 128, 0, stream>>>(x, slot_tok, exp_in);

  // bf16 casts / weight transposes
  k_cast_bf16<<<(TOK * DM / 4) / 256, 256, 0, stream>>>(x, xb, (size_t)TOK * DM);
  k_transpose<<<dim3(DM / 32, HD / 32), 256, 0, stream>>>(skey, skT, DM, HD, HD);
  k_transpose<<<dim3(HD / 32, DM / 32), 256, 0, stream>>>(sval, svT, HD, DM, DM);
  for (int e = 0; e < NE; ++e) {
    k_transpose<<<dim3(DM / 32, HD / 32), 256, 0, stream>>>(
        keys + (size_t)e * HD, keysT + (size_t)e * HD * DM, DM, HD, NE * HD);
    k_transpose<<<dim3(HD / 32, DM / 32), 256, 0, stream>>>(
        vals + (size_t)e * DM, valsT + (size_t)e * DM * HD, HD, DM, NE * DM);
  }

  // shared expert: sh = gelu(xb @ skT + skeyb); out = sh @ svT + svalb
  k_gemm8p<0><<<(TOK/256)*(HD/256), 512, 0, stream>>>(
      xb, 0, DM, skT, 0, DM, sh, 0, HD, skeyb, 0, DM, TOK/256, HD/256);
  k_gemm8p<2><<<(TOK/256)*(DM/256), 512, 0, stream>>>(
      sh, 0, HD, svT, 0, HD, out, 0, DM, svalb, 0, HD, TOK/256, DM/256);

  // MoE experts
  k_gemm8p<0><<<(MEP/256)*(HD/256)*NE, 512, 0, stream>>>(
      exp_in, (size_t)MEP * DM, DM, keysT, (size_t)HD * DM, DM,
      h, (size_t)MEP * HD, HD, keyb, HD, DM, MEP/256, HD/256);
  k_gemm8p<1><<<(MEP/256)*(DM/256)*NE, 512, 0, stream>>>(
      h, (size_t)MEP * HD, HD, valsT, (size_t)DM * HD, HD,
      eo, (size_t)MEP * DM, DM, valb, DM, HD, MEP/256, DM/256);

  // combine: out += gate * eo[slot]
  k_combine<<<TOK, 256, 0, stream>>>(tok_slot, gsel, eo, out);
}